// Round 6
// baseline (324.400 us; speedup 1.0000x reference)
//
#include <hip/hip_runtime.h>

#define BT    16
#define NN    10242
#define CC    64
#define KK    9
#define NBR_  7
#define OO    64
#define MT    16            // rows (nodes) per block -> LDS 18.7KB -> 8 blocks/CU
#define RS    584           // LDS itp row stride in bf16 (16B-aligned, bank-spread)
#define KT    18            // K tiles of 32
#define BG    4             // bt per block = 2 pk-fma pairs sharing m/index

using frag  = __attribute__((ext_vector_type(8))) short;   // 8 bf16 (4 VGPRs)
using f32x4 = __attribute__((ext_vector_type(4))) float;
using f32x2 = __attribute__((ext_vector_type(2))) float;

static __device__ __forceinline__ unsigned short f2bf(float f) {
    union { float f; unsigned u; } v; v.f = f;
    unsigned r = v.u + 0x7fffu + ((v.u >> 16) & 1u);   // RNE
    return (unsigned short)(r >> 16);
}

// q-permutation shared by producer and weight pack:
//   k in [0,8): q = (k>>2)*256 + c*4 + (k&3);  k==8: q = 512 + c
// wb[((t*4+ct)*64+lane)*8+j] = bf16(w[o][c][k]), q=t*32+(lane>>4)*8+j, o=ct*16+(lane&15)
__global__ void pack_w_kernel(const float* __restrict__ w, unsigned short* __restrict__ wb) {
    int i = blockIdx.x * blockDim.x + threadIdx.x;
    if (i >= KT * 4 * 64 * 8) return;
    int j  = i & 7;
    int l  = (i >> 3) & 63;
    int ct = (i >> 9) & 3;
    int t  = i >> 11;
    int q  = t * 32 + (l >> 4) * 8 + j;
    int o  = ct * 16 + (l & 15);
    int c, k;
    if (q < 512) { c = (q & 255) >> 2; k = (q >> 8) * 4 + (q & 3); }
    else         { c = q - 512;        k = 8; }
    wb[i] = f2bf(w[(o * CC + c) * KK + k]);
}

__global__ __launch_bounds__(256, 6) void sphere_conv_kernel(
    const float* __restrict__ x,      // (BT, N, C)
    const int*   __restrict__ index,  // (N, NBR)
    const float* __restrict__ m,      // (N, NBR, K)
    const unsigned short* __restrict__ wb,  // packed B frags (bf16 bits)
    const float* __restrict__ bias,   // (O,)
    float*       __restrict__ out)    // (BT, N, O)
{
    __shared__ unsigned short itp_s[MT * RS];   // 18688 B

    const int tid  = threadIdx.x;
    const int btg  = blockIdx.x;                // bt group 0..3
    const int n0   = blockIdx.y * MT;
    const int w    = tid >> 6;
    const int lane = tid & 63;

    // consumer geometry (wave = 16 rows x 16 cols, ct = wave id)
    const int ct   = w;
    const int am   = lane & 15;
    const int half = lane >> 4;
    const unsigned short* arow = &itp_s[am * RS + half * 8];
    const frag* wbf = (const frag*)wb;
    const float bo = bias[ct * 16 + am];

    #pragma unroll
    for (int ip = 0; ip < BG / 2; ++ip) {
        const int bt0 = btg * BG + ip * 2;          // pair (bt0, bt0+1)
        const float* xb0 = x + (size_t)bt0 * NN * CC;

        uint2 sq0[4], sq1[4];                       // bt1 stash (packed rows)
        unsigned short sh8[4];

        // ---- Producer: 4 rows/wave, both bt of the pair via v_pk_fma_f32 ----
        #pragma unroll
        for (int r = 0; r < 4; ++r) {
            const int ns = w * 4 + r;
            int n  = n0 + ns;
            int nu = __builtin_amdgcn_readfirstlane(n < NN ? n : (NN - 1));
            const int*   idp = index + nu * NBR_;       // s_load (L2/K$-warm, ip>0)
            const float* mp  = m + nu * (NBR_ * KK);    // s_load, shared by both bt
            f32x2 xv[NBR_];
            #pragma unroll
            for (int j = 0; j < NBR_; ++j) {
                const int idj = idp[j];
                const float* p = xb0 + (size_t)idj * CC + lane;  // coalesced 256B
                xv[j][0] = p[0];                       // bt0 slice
                xv[j][1] = p[NN * CC];                 // bt1 slice (+2.62MB)
            }
            f32x2 acc[KK];
            #pragma unroll
            for (int k = 0; k < KK; ++k) acc[k] = (f32x2){0.f, 0.f};
            #pragma unroll
            for (int j = 0; j < NBR_; ++j) {
                #pragma unroll
                for (int k = 0; k < KK; ++k) {
                    const float mjk = mp[j * KK + k];
                    acc[k] = __builtin_elementwise_fma(xv[j], (f32x2){mjk, mjk}, acc[k]);
                }
            }
            unsigned short h0[KK], h1[KK];
            #pragma unroll
            for (int k = 0; k < KK; ++k) { h0[k] = f2bf(acc[k][0]); h1[k] = f2bf(acc[k][1]); }
            uint2 q0, q1;
            q0.x = (unsigned)h0[0] | ((unsigned)h0[1] << 16);
            q0.y = (unsigned)h0[2] | ((unsigned)h0[3] << 16);
            q1.x = (unsigned)h0[4] | ((unsigned)h0[5] << 16);
            q1.y = (unsigned)h0[6] | ((unsigned)h0[7] << 16);
            unsigned short* row = &itp_s[ns * RS];
            *(uint2*)(&row[lane * 4])       = q0;      // bt0 -> LDS now
            *(uint2*)(&row[256 + lane * 4]) = q1;
            row[512 + lane] = h0[8];
            sq0[r].x = (unsigned)h1[0] | ((unsigned)h1[1] << 16);   // bt1 -> stash
            sq0[r].y = (unsigned)h1[2] | ((unsigned)h1[3] << 16);
            sq1[r].x = (unsigned)h1[4] | ((unsigned)h1[5] << 16);
            sq1[r].y = (unsigned)h1[6] | ((unsigned)h1[7] << 16);
            sh8[r]   = h1[8];
        }
        __syncthreads();

        // ---- Consume bt0 ----
        {
            f32x4 acc = (f32x4){0.f, 0.f, 0.f, 0.f};
            #pragma unroll
            for (int t = 0; t < KT; ++t) {
                const frag a = *(const frag*)(arow + t * 32);   // ds_read_b128
                const frag b = wbf[(t * 4 + ct) * 64 + lane];   // L2-hot
                acc = __builtin_amdgcn_mfma_f32_16x16x32_bf16(a, b, acc, 0, 0, 0);
            }
            const size_t obase = (size_t)bt0 * NN * OO;
            const int o = ct * 16 + am;
            #pragma unroll
            for (int i = 0; i < 4; ++i) {
                const int n = n0 + half * 4 + i;
                if (n < NN) out[obase + (size_t)n * OO + o] = acc[i] + bo;
            }
        }
        __syncthreads();

        // ---- Write bt1 tile from stash ----
        #pragma unroll
        for (int r = 0; r < 4; ++r) {
            const int ns = w * 4 + r;
            unsigned short* row = &itp_s[ns * RS];
            *(uint2*)(&row[lane * 4])       = sq0[r];
            *(uint2*)(&row[256 + lane * 4]) = sq1[r];
            row[512 + lane] = sh8[r];
        }
        __syncthreads();

        // ---- Consume bt1 ----
        {
            f32x4 acc = (f32x4){0.f, 0.f, 0.f, 0.f};
            #pragma unroll
            for (int t = 0; t < KT; ++t) {
                const frag a = *(const frag*)(arow + t * 32);
                const frag b = wbf[(t * 4 + ct) * 64 + lane];
                acc = __builtin_amdgcn_mfma_f32_16x16x32_bf16(a, b, acc, 0, 0, 0);
            }
            const size_t obase = (size_t)(bt0 + 1) * NN * OO;
            const int o = ct * 16 + am;
            #pragma unroll
            for (int i = 0; i < 4; ++i) {
                const int n = n0 + half * 4 + i;
                if (n < NN) out[obase + (size_t)n * OO + o] = acc[i] + bo;
            }
        }
        __syncthreads();    // protect LDS before next pair's producer
    }
}

extern "C" void kernel_launch(void* const* d_in, const int* in_sizes, int n_in,
                              void* d_out, int out_size, void* d_ws, size_t ws_size,
                              hipStream_t stream) {
    const float* x      = (const float*)d_in[0];
    const int*   index  = (const int*)  d_in[1];
    const float* m      = (const float*)d_in[2];
    const float* conv_w = (const float*)d_in[3];
    const float* conv_b = (const float*)d_in[4];
    float* out = (float*)d_out;
    unsigned short* wb = (unsigned short*)d_ws;   // 73728 B

    {   // pack weights into MFMA B-fragment order
        const int total = KT * 4 * 64 * 8;
        pack_w_kernel<<<(total + 255) / 256, 256, 0, stream>>>(conv_w, wb);
    }
    {   // fused gather + interp + MFMA conv, 4 bt per block
        dim3 grid(BT / BG, (NN + MT - 1) / MT);   // (4, 641)
        sphere_conv_kernel<<<grid, 256, 0, stream>>>(x, index, m, wb, conv_b, out);
    }
}

// Round 7
// 148.960 us; speedup vs baseline: 2.1778x; 2.1778x over previous
//
#include <hip/hip_runtime.h>

#define BT    16
#define NN    10242
#define CC    64
#define KK    9
#define NBR_  7
#define OO    64
#define MT    16            // rows (nodes) per block -> LDS 18.7KB -> 8 blocks/CU
#define RS    584           // LDS itp row stride in bf16 (16B-aligned, bank-spread)
#define KT    18            // K tiles of 32
#define BG    2             // bt per block (looped, no register stash)

using frag  = __attribute__((ext_vector_type(8))) short;   // 8 bf16 (4 VGPRs)
using f32x4 = __attribute__((ext_vector_type(4))) float;
using f32x2 = __attribute__((ext_vector_type(2))) float;

static __device__ __forceinline__ unsigned short f2bf(float f) {
    union { float f; unsigned u; } v; v.f = f;
    unsigned r = v.u + 0x7fffu + ((v.u >> 16) & 1u);   // RNE
    return (unsigned short)(r >> 16);
}

// q-permutation shared by producer and weight pack:
//   k in [0,8): q = (k>>2)*256 + c*4 + (k&3);  k==8: q = 512 + c
// wb[((t*4+ct)*64+lane)*8+j] = bf16(w[o][c][k]), q=t*32+(lane>>4)*8+j, o=ct*16+(lane&15)
__global__ void pack_w_kernel(const float* __restrict__ w, unsigned short* __restrict__ wb) {
    int i = blockIdx.x * blockDim.x + threadIdx.x;
    if (i >= KT * 4 * 64 * 8) return;
    int j  = i & 7;
    int l  = (i >> 3) & 63;
    int ct = (i >> 9) & 3;
    int t  = i >> 11;
    int q  = t * 32 + (l >> 4) * 8 + j;
    int o  = ct * 16 + (l & 15);
    int c, k;
    if (q < 512) { c = (q & 255) >> 2; k = (q >> 8) * 4 + (q & 3); }
    else         { c = q - 512;        k = 8; }
    wb[i] = f2bf(w[(o * CC + c) * KK + k]);
}

__global__ __launch_bounds__(256, 6) void sphere_conv_kernel(
    const float* __restrict__ x,      // (BT, N, C)
    const int*   __restrict__ index,  // (N, NBR)
    const float* __restrict__ m,      // (N, NBR, K)
    const unsigned short* __restrict__ wb,  // packed B frags (bf16 bits)
    const float* __restrict__ bias,   // (O,)
    float*       __restrict__ out)    // (BT, N, O)
{
    __shared__ unsigned short itp_s[MT * RS];   // 18688 B

    const int tid  = threadIdx.x;
    const int btg  = blockIdx.x;                // 0..7 (fastest -> XCD L2 locality)
    const int n0   = blockIdx.y * MT;
    const int w    = tid >> 6;
    const int lane = tid & 63;

    // consumer geometry (wave = 16 rows x 16 cols, ct = wave id)
    const int ct   = w;
    const int am   = lane & 15;
    const int half = lane >> 4;
    const unsigned short* arow = &itp_s[am * RS + half * 8];
    const frag* wbf = (const frag*)wb;
    const float bo = bias[ct * 16 + am];

    #pragma unroll
    for (int ib = 0; ib < BG; ++ib) {
        const int bt = btg * BG + ib;
        const float* xbt = x + (size_t)bt * NN * CC;

        // ---- Producer phase A: issue ALL 28 gathers (one latency exposure) ----
        float xv[4][NBR_];
        const float* mrow[4];
        #pragma unroll
        for (int r = 0; r < 4; ++r) {
            const int ns = w * 4 + r;
            int n  = n0 + ns;
            int nu = __builtin_amdgcn_readfirstlane(n < NN ? n : (NN - 1));
            const int* idp = index + nu * NBR_;        // s_load (K$-warm at ib=1)
            mrow[r] = m + nu * (NBR_ * KK);
            #pragma unroll
            for (int j = 0; j < NBR_; ++j)
                xv[r][j] = xbt[(size_t)idp[j] * CC + lane];   // coalesced 256B
        }

        // ---- Producer phase B: interp FMAs (pk over k-pairs) + pack ----------
        #pragma unroll
        for (int r = 0; r < 4; ++r) {
            const int ns = w * 4 + r;
            const float* mp = mrow[r];                 // s_load (K$-warm at ib=1)
            f32x2 a01 = {0.f, 0.f}, a23 = {0.f, 0.f};
            f32x2 a45 = {0.f, 0.f}, a67 = {0.f, 0.f};
            float a8 = 0.f;
            #pragma unroll
            for (int j = 0; j < NBR_; ++j) {
                const float xj = xv[r][j];
                const f32x2 xx = {xj, xj};
                a01 = __builtin_elementwise_fma(xx, (f32x2){mp[j*KK+0], mp[j*KK+1]}, a01);
                a23 = __builtin_elementwise_fma(xx, (f32x2){mp[j*KK+2], mp[j*KK+3]}, a23);
                a45 = __builtin_elementwise_fma(xx, (f32x2){mp[j*KK+4], mp[j*KK+5]}, a45);
                a67 = __builtin_elementwise_fma(xx, (f32x2){mp[j*KK+6], mp[j*KK+7]}, a67);
                a8  = fmaf(xj, mp[j*KK+8], a8);
            }
            uint2 q0, q1;
            q0.x = (unsigned)f2bf(a01[0]) | ((unsigned)f2bf(a01[1]) << 16);
            q0.y = (unsigned)f2bf(a23[0]) | ((unsigned)f2bf(a23[1]) << 16);
            q1.x = (unsigned)f2bf(a45[0]) | ((unsigned)f2bf(a45[1]) << 16);
            q1.y = (unsigned)f2bf(a67[0]) | ((unsigned)f2bf(a67[1]) << 16);
            unsigned short* row = &itp_s[ns * RS];
            *(uint2*)(&row[lane * 4])       = q0;      // 8B, 2-way banks = free
            *(uint2*)(&row[256 + lane * 4]) = q1;
            row[512 + lane] = f2bf(a8);
        }
        __syncthreads();

        // ---- Consumer: dual MFMA chains (break 18-deep acc dependency) -------
        {
            f32x4 aa = (f32x4){0.f, 0.f, 0.f, 0.f};
            f32x4 ab = (f32x4){0.f, 0.f, 0.f, 0.f};
            #pragma unroll
            for (int t = 0; t < KT; t += 2) {
                const frag a0 = *(const frag*)(arow + t * 32);        // ds_read_b128
                const frag b0 = wbf[(t * 4 + ct) * 64 + lane];        // L2-hot
                aa = __builtin_amdgcn_mfma_f32_16x16x32_bf16(a0, b0, aa, 0, 0, 0);
                const frag a1 = *(const frag*)(arow + (t + 1) * 32);
                const frag b1 = wbf[((t + 1) * 4 + ct) * 64 + lane];
                ab = __builtin_amdgcn_mfma_f32_16x16x32_bf16(a1, b1, ab, 0, 0, 0);
            }
            const size_t obase = (size_t)bt * NN * OO;
            const int o = ct * 16 + am;
            #pragma unroll
            for (int i = 0; i < 4; ++i) {
                const int n = n0 + half * 4 + i;
                if (n < NN) out[obase + (size_t)n * OO + o] = aa[i] + ab[i] + bo;
            }
        }
        __syncthreads();    // protect LDS before next bt's producer
    }
}

extern "C" void kernel_launch(void* const* d_in, const int* in_sizes, int n_in,
                              void* d_out, int out_size, void* d_ws, size_t ws_size,
                              hipStream_t stream) {
    const float* x      = (const float*)d_in[0];
    const int*   index  = (const int*)  d_in[1];
    const float* m      = (const float*)d_in[2];
    const float* conv_w = (const float*)d_in[3];
    const float* conv_b = (const float*)d_in[4];
    float* out = (float*)d_out;
    unsigned short* wb = (unsigned short*)d_ws;   // 73728 B

    {   // pack weights into MFMA B-fragment order
        const int total = KT * 4 * 64 * 8;
        pack_w_kernel<<<(total + 255) / 256, 256, 0, stream>>>(conv_w, wb);
    }
    {   // fused gather + interp + MFMA conv, 2 bt looped per block
        dim3 grid(BT / BG, (NN + MT - 1) / MT);   // (8, 641)
        sphere_conv_kernel<<<grid, 256, 0, stream>>>(x, index, m, wb, conv_b, out);
    }
}